// Round 1
// baseline (1201.868 us; speedup 1.0000x reference)
//
#include <hip/hip_runtime.h>

#define NN 100000
#define NE 800000

// ---------------- prep: build combined weight matrices ----------------
// wc0: 18x16  rows 0..5 = W0n[0], 6..11 = W0n[1], 12..17 = W0r[0]+W0r[1]
// wc1: 48x32  rows 0..15 = W1n[0], 16..31 = W1n[1], 32..47 = W1r[0]+W1r[1]+P1
// wc2: 256x64 rows 0..223 = W2n[0..6], 224..255 = sum_r W2r[r] + P2
__global__ __launch_bounds__(256) void prep_weights(
    const float* __restrict__ W0n, const float* __restrict__ W0r, const float* __restrict__ b0,
    const float* __restrict__ W1n, const float* __restrict__ W1r, const float* __restrict__ b1,
    const float* __restrict__ P1,  const float* __restrict__ pb1,
    const float* __restrict__ W2n, const float* __restrict__ W2r, const float* __restrict__ b2,
    const float* __restrict__ P2,  const float* __restrict__ pb2,
    float* __restrict__ wc0, float* __restrict__ bc0,
    float* __restrict__ wc1, float* __restrict__ bc1,
    float* __restrict__ wc2, float* __restrict__ bc2)
{
    int tid = threadIdx.x;
    for (int t = tid; t < 18 * 16; t += 256) {
        int row = t >> 4, col = t & 15;
        float v;
        if (row < 6)       v = W0n[row * 16 + col];
        else if (row < 12) v = W0n[96 + (row - 6) * 16 + col];
        else               v = W0r[(row - 12) * 16 + col] + W0r[96 + (row - 12) * 16 + col];
        wc0[t] = v;
    }
    for (int t = tid; t < 16; t += 256) bc0[t] = b0[t] + b0[16 + t];

    for (int t = tid; t < 48 * 32; t += 256) {
        int row = t >> 5, col = t & 31;
        float v;
        if (row < 16)      v = W1n[row * 32 + col];
        else if (row < 32) v = W1n[512 + (row - 16) * 32 + col];
        else { int rr = row - 32; v = W1r[rr * 32 + col] + W1r[512 + rr * 32 + col] + P1[rr * 32 + col]; }
        wc1[t] = v;
    }
    for (int t = tid; t < 32; t += 256) bc1[t] = b1[t] + b1[32 + t] + pb1[t];

    for (int t = tid; t < 256 * 64; t += 256) {
        int row = t >> 6, col = t & 63;
        float v;
        if (row < 224) v = W2n[t];
        else {
            int rr = row - 224;
            v = P2[rr * 64 + col];
            #pragma unroll
            for (int r = 0; r < 7; ++r) v += W2r[r * 2048 + rr * 64 + col];
        }
        wc2[t] = v;
    }
    for (int t = tid; t < 64; t += 256) {
        float v = pb2[t];
        #pragma unroll
        for (int r = 0; r < 7; ++r) v += b2[r * 64 + t];
        bc2[t] = v;
    }
}

// ---------------- scatter: msg[dst] += feat[src], thread per (edge, feature) ----------------
template <int DIM>
__global__ __launch_bounds__(256) void scatter_feat(const float* __restrict__ feat,
                                                    const int* __restrict__ src,
                                                    const int* __restrict__ dst,
                                                    float* __restrict__ msg)
{
    int t = blockIdx.x * 256 + threadIdx.x;
    int e, f;
    if constexpr (DIM == 6) { e = t / 6; f = t - e * 6; }
    else                    { e = t / DIM; f = t & (DIM - 1); }
    if (e >= NE) return;
    atomicAdd(&msg[(size_t)dst[e] * DIM + f], feat[(size_t)src[e] * DIM + f]);
}

__global__ __launch_bounds__(256) void count_edges(const int* __restrict__ dst, float* __restrict__ cnt)
{
    int t = blockIdx.x * 256 + threadIdx.x;
    if (t < NE) atomicAdd(&cnt[dst[t]], 1.0f);
}

// ---------------- per-node transform helpers ----------------
template <int DIN, int DOUT>
__device__ __forceinline__ void accum_block(const float* __restrict__ rowp, float scale,
                                            const float* __restrict__ W, float* acc)
{
    float v[DIN];
    if constexpr (DIN % 4 == 0) {
        const float4* r4 = reinterpret_cast<const float4*>(rowp);
        #pragma unroll
        for (int k4 = 0; k4 < DIN / 4; ++k4) {
            float4 t = r4[k4];
            v[4 * k4 + 0] = t.x; v[4 * k4 + 1] = t.y; v[4 * k4 + 2] = t.z; v[4 * k4 + 3] = t.w;
        }
    } else {
        #pragma unroll
        for (int k = 0; k < DIN; ++k) v[k] = rowp[k];
    }
    for (int k = 0; k < DIN; ++k) {
        float s = v[k] * scale;
        const float* w = W + k * DOUT;
        #pragma unroll
        for (int j = 0; j < DOUT; ++j) acc[j] = fmaf(s, w[j], acc[j]);
    }
}

template <int DOUT>
__device__ __forceinline__ void store_row(float* __restrict__ out, int n, const float* acc, bool relu)
{
    float4* o = reinterpret_cast<float4*>(out + (size_t)n * DOUT);
    #pragma unroll
    for (int j4 = 0; j4 < DOUT / 4; ++j4) {
        float a = acc[4 * j4], b = acc[4 * j4 + 1], c = acc[4 * j4 + 2], d = acc[4 * j4 + 3];
        if (relu) { a = fmaxf(a, 0.f); b = fmaxf(b, 0.f); c = fmaxf(c, 0.f); d = fmaxf(d, 0.f); }
        o[j4] = make_float4(a, b, c, d);
    }
}

__global__ __launch_bounds__(256) void transform0(const float* __restrict__ msgA, const float* __restrict__ msgB,
                                                  const float* __restrict__ x, const float* __restrict__ Wc,
                                                  const float* __restrict__ bc, float* __restrict__ out)
{
    int n = blockIdx.x * 256 + threadIdx.x;
    if (n >= NN) return;
    float acc[16];
    #pragma unroll
    for (int j = 0; j < 16; ++j) acc[j] = bc[j];
    accum_block<6, 16>(msgA + (size_t)n * 6, 1.0f, Wc, acc);
    accum_block<6, 16>(msgB + (size_t)n * 6, 1.0f, Wc + 96, acc);
    accum_block<6, 16>(x + (size_t)n * 6, 1.0f, Wc + 192, acc);
    store_row<16>(out, n, acc, false);
}

__global__ __launch_bounds__(256) void transform1(const float* __restrict__ msgA, const float* __restrict__ msgB,
                                                  const float* __restrict__ h0, const float* __restrict__ Wc,
                                                  const float* __restrict__ bc, float* __restrict__ out)
{
    int n = blockIdx.x * 256 + threadIdx.x;
    if (n >= NN) return;
    float acc[32];
    #pragma unroll
    for (int j = 0; j < 32; ++j) acc[j] = bc[j];
    accum_block<16, 32>(msgA + (size_t)n * 16, 1.0f, Wc, acc);
    accum_block<16, 32>(msgB + (size_t)n * 16, 1.0f, Wc + 512, acc);
    accum_block<16, 32>(h0 + (size_t)n * 16, 1.0f, Wc + 1024, acc);
    store_row<32>(out, n, acc, true);
}

__global__ __launch_bounds__(256) void transform2_full(const float* __restrict__ msg, const float* __restrict__ h1,
                                                       const float* __restrict__ cnt, const float* __restrict__ Wc,
                                                       const float* __restrict__ bc, float* __restrict__ out)
{
    int n = blockIdx.x * 256 + threadIdx.x;
    if (n >= NN) return;
    float acc[64];
    #pragma unroll
    for (int j = 0; j < 64; ++j) acc[j] = bc[j];
    float i2 = 1.0f / fmaxf(cnt[n], 1.0f);
    float i3 = 1.0f / fmaxf(cnt[NN + n], 1.0f);
    float i6 = 1.0f / fmaxf(cnt[2 * NN + n], 1.0f);
    #pragma unroll 1
    for (int r = 0; r < 8; ++r) {
        const float* rowp = (r < 7) ? (msg + ((size_t)r * NN + (size_t)n) * 32)
                                    : (h1 + (size_t)n * 32);
        float scale = (r == 2) ? i2 : (r == 3) ? i3 : (r == 6) ? i6 : 1.0f;
        accum_block<32, 64>(rowp, scale, Wc + r * 2048, acc);
    }
    store_row<64>(out, n, acc, true);
}

// Sequential-workspace fallback kernels
__global__ __launch_bounds__(256) void transform2_init(const float* __restrict__ h1, const float* __restrict__ Wc,
                                                       const float* __restrict__ bc, float* __restrict__ out)
{
    int n = blockIdx.x * 256 + threadIdx.x;
    if (n >= NN) return;
    float acc[64];
    #pragma unroll
    for (int j = 0; j < 64; ++j) acc[j] = bc[j];
    accum_block<32, 64>(h1 + (size_t)n * 32, 1.0f, Wc + 224 * 64, acc);
    store_row<64>(out, n, acc, false);
}

__global__ __launch_bounds__(256) void transform2_acc(const float* __restrict__ msg, const float* __restrict__ cnt,
                                                      const float* __restrict__ Wn, float* __restrict__ out, int do_relu)
{
    int n = blockIdx.x * 256 + threadIdx.x;
    if (n >= NN) return;
    float acc[64];
    const float4* o4 = reinterpret_cast<const float4*>(out + (size_t)n * 64);
    #pragma unroll
    for (int j4 = 0; j4 < 16; ++j4) {
        float4 t = o4[j4];
        acc[4 * j4] = t.x; acc[4 * j4 + 1] = t.y; acc[4 * j4 + 2] = t.z; acc[4 * j4 + 3] = t.w;
    }
    float scale = cnt ? (1.0f / fmaxf(cnt[n], 1.0f)) : 1.0f;
    accum_block<32, 64>(msg + (size_t)n * 32, scale, Wn, acc);
    store_row<64>(out, n, acc, do_relu != 0);
}

// ---------------- launch ----------------
extern "C" void kernel_launch(void* const* d_in, const int* in_sizes, int n_in,
                              void* d_out, int out_size, void* d_ws, size_t ws_size,
                              hipStream_t stream)
{
    const float* x = (const float*)d_in[0];
    const int* e_src[9]; const int* e_dst[9];
    for (int i = 0; i < 9; ++i) { const int* p = (const int*)d_in[1 + i]; e_src[i] = p; e_dst[i] = p + NE; }
    const float* W0n = (const float*)d_in[10]; const float* W0r = (const float*)d_in[11];
    const float* b0  = (const float*)d_in[12];
    const float* W1n = (const float*)d_in[13]; const float* W1r = (const float*)d_in[14];
    const float* b1  = (const float*)d_in[15];
    const float* P1  = (const float*)d_in[16]; const float* pb1 = (const float*)d_in[17];
    const float* W2n = (const float*)d_in[18]; const float* W2r = (const float*)d_in[19];
    const float* b2  = (const float*)d_in[20];
    const float* P2  = (const float*)d_in[21]; const float* pb2 = (const float*)d_in[22];
    float* out = (float*)d_out;
    char* ws = (char*)d_ws;

    size_t off = 0;
    auto alloc = [&](size_t b) { size_t o = off; off += (b + 255) & ~(size_t)255; return o; };
    size_t o_h0  = alloc((size_t)NN * 16 * 4);
    size_t o_h1  = alloc((size_t)NN * 32 * 4);
    size_t o_wc0 = alloc(288 * 4);  size_t o_bc0 = alloc(16 * 4);
    size_t o_wc1 = alloc(1536 * 4); size_t o_bc1 = alloc(32 * 4);
    size_t o_wc2 = alloc(16384 * 4); size_t o_bc2 = alloc(64 * 4);
    size_t o_msgstart = off;
    // full-parallel layout
    size_t o_m0 = alloc((size_t)2 * NN * 6 * 4);
    size_t o_m1 = alloc((size_t)2 * NN * 16 * 4);
    size_t o_m2 = alloc((size_t)7 * NN * 32 * 4);
    size_t o_cntF = alloc((size_t)3 * NN * 4);
    size_t full_total = off;
    bool full = (ws_size >= full_total);
    size_t o_msgS = 0, o_cntS = 0;
    if (!full) {
        off = o_msgstart;
        o_msgS = alloc((size_t)NN * 32 * 4);   // >= 2*N*6 and == 2*N*16
        o_cntS = alloc((size_t)3 * NN * 4);
    }

    float* h0  = (float*)(ws + o_h0);
    float* h1  = (float*)(ws + o_h1);
    float* wc0 = (float*)(ws + o_wc0); float* bc0 = (float*)(ws + o_bc0);
    float* wc1 = (float*)(ws + o_wc1); float* bc1 = (float*)(ws + o_bc1);
    float* wc2 = (float*)(ws + o_wc2); float* bc2 = (float*)(ws + o_bc2);

    const int gridN   = (NN + 255) / 256;
    const int gridE6  = (NE * 6 + 255) / 256;
    const int gridE16 = (NE * 16) / 256;
    const int gridE32 = (NE * 32) / 256;
    const int gridE   = (NE + 255) / 256;
    dim3 B(256);

    prep_weights<<<1, B, 0, stream>>>(W0n, W0r, b0, W1n, W1r, b1, P1, pb1,
                                      W2n, W2r, b2, P2, pb2,
                                      wc0, bc0, wc1, bc1, wc2, bc2);

    if (full) {
        float* m0  = (float*)(ws + o_m0);
        float* m1  = (float*)(ws + o_m1);
        float* m2  = (float*)(ws + o_m2);
        float* cnt = (float*)(ws + o_cntF);
        hipMemsetAsync(ws + o_m0, 0, full_total - o_m0, stream);

        scatter_feat<6><<<gridE6, B, 0, stream>>>(x, e_src[0], e_dst[0], m0);
        scatter_feat<6><<<gridE6, B, 0, stream>>>(x, e_src[1], e_dst[1], m0 + (size_t)NN * 6);
        transform0<<<gridN, B, 0, stream>>>(m0, m0 + (size_t)NN * 6, x, wc0, bc0, h0);

        scatter_feat<16><<<gridE16, B, 0, stream>>>(h0, e_src[0], e_dst[0], m1);
        scatter_feat<16><<<gridE16, B, 0, stream>>>(h0, e_src[1], e_dst[1], m1 + (size_t)NN * 16);
        transform1<<<gridN, B, 0, stream>>>(m1, m1 + (size_t)NN * 16, h0, wc1, bc1, h1);

        for (int r = 0; r < 7; ++r)
            scatter_feat<32><<<gridE32, B, 0, stream>>>(h1, e_src[2 + r], e_dst[2 + r],
                                                        m2 + (size_t)r * NN * 32);
        count_edges<<<gridE, B, 0, stream>>>(e_dst[4], cnt);
        count_edges<<<gridE, B, 0, stream>>>(e_dst[5], cnt + NN);
        count_edges<<<gridE, B, 0, stream>>>(e_dst[8], cnt + 2 * NN);
        transform2_full<<<gridN, B, 0, stream>>>(m2, h1, cnt, wc2, bc2, out);
    } else {
        float* msg = (float*)(ws + o_msgS);
        float* cnt = (float*)(ws + o_cntS);

        hipMemsetAsync(msg, 0, (size_t)2 * NN * 6 * 4, stream);
        scatter_feat<6><<<gridE6, B, 0, stream>>>(x, e_src[0], e_dst[0], msg);
        scatter_feat<6><<<gridE6, B, 0, stream>>>(x, e_src[1], e_dst[1], msg + (size_t)NN * 6);
        transform0<<<gridN, B, 0, stream>>>(msg, msg + (size_t)NN * 6, x, wc0, bc0, h0);

        hipMemsetAsync(msg, 0, (size_t)2 * NN * 16 * 4, stream);
        scatter_feat<16><<<gridE16, B, 0, stream>>>(h0, e_src[0], e_dst[0], msg);
        scatter_feat<16><<<gridE16, B, 0, stream>>>(h0, e_src[1], e_dst[1], msg + (size_t)NN * 16);
        transform1<<<gridN, B, 0, stream>>>(msg, msg + (size_t)NN * 16, h0, wc1, bc1, h1);

        hipMemsetAsync(cnt, 0, (size_t)3 * NN * 4, stream);
        count_edges<<<gridE, B, 0, stream>>>(e_dst[4], cnt);
        count_edges<<<gridE, B, 0, stream>>>(e_dst[5], cnt + NN);
        count_edges<<<gridE, B, 0, stream>>>(e_dst[8], cnt + 2 * NN);
        transform2_init<<<gridN, B, 0, stream>>>(h1, wc2, bc2, out);
        for (int r = 0; r < 7; ++r) {
            hipMemsetAsync(msg, 0, (size_t)NN * 32 * 4, stream);
            scatter_feat<32><<<gridE32, B, 0, stream>>>(h1, e_src[2 + r], e_dst[2 + r], msg);
            const float* cp = (r == 2) ? cnt : (r == 3) ? cnt + NN : (r == 6) ? cnt + 2 * NN : nullptr;
            transform2_acc<<<gridN, B, 0, stream>>>(msg, cp, wc2 + r * 2048, out, (r == 6) ? 1 : 0);
        }
    }
}